// Round 14
// baseline (112.142 us; speedup 1.0000x reference)
//
#include <hip/hip_runtime.h>
#include <hip/hip_fp16.h>
#include <cstdint>

#define IN_F   4096
#define OUT_F  4096
#define BS     64      // sparsity block size
#define NB     64      // blocks per weight dim
#define N_TOK  8192
#define TM     256     // token tile per workgroup (4 waves x 64 rows)
#define NMT    (N_TOK / TM)   // 32 token tiles

typedef __attribute__((ext_vector_type(8))) _Float16       f16x8;
typedef __attribute__((ext_vector_type(8))) unsigned short u16x8;
typedef __attribute__((ext_vector_type(4))) unsigned short u16x4;
typedef __attribute__((ext_vector_type(4))) float          f32x4;

// ---------------- workspace layout (bytes) ----------------
// xt: 2048 tiles (mt,kb) x 32 KB (u16[256][64], pre-swizzled)   -- r8-proven
// wt: 4096 slots (br,si) x 8 KB  (u16[64][64],  pre-swizzled)
#define WS_XT_OFF      0ull
#define WS_XT_BYTES    (2048ull * 32768ull)            // 64 MiB
#define WS_WT_OFF      (WS_XT_OFF + WS_XT_BYTES)
#define WS_WT_BYTES    (4096ull * 8192ull)             // 32 MiB
#define WS_NEEDED      (WS_WT_OFF + WS_WT_BYTES)       // 96 MiB

// wave-uniform ballot of the block-constant mask row `br`
__device__ __forceinline__ unsigned long long mask_ballot(
        const float* __restrict__ mask, int br, int lane) {
    float mv = mask[(size_t)(br * BS) * IN_F + (size_t)lane * BS];
    return __ballot(mv != 0.0f);
}

// pack 8 fp32 -> 8 fp16 (RNE) bit patterns
__device__ __forceinline__ u16x8 pack8(f32x4 a, f32x4 b) {
    u16x8 o;
#pragma unroll
    for (int j = 0; j < 4; ++j) o[j]     = __half_as_ushort(__float2half_rn(a[j]));
#pragma unroll
    for (int j = 0; j < 4; ++j) o[4 + j] = __half_as_ushort(__float2half_rn(b[j]));
    return o;
}

// ---------------------------------------------------------------------------
// Kernel 1 (merged convert):
//  blocks [0,1024): x -> packed swizzled xt tiles via LDS TRANSPOSE.
//    WG = (mt, 8-row block). Per 512-col chunk: linear 1KB/wave reads,
//    fp16+swizzle into LDS [8kb][8row][64], then 1KB/wave contiguous writes
//    into 8 tiles. Both global sides fully coalesced — no strided DRAM access.
//  blocks [1024,1024+4096): kept W blocks -> packed pre-swizzled wt
//    (inline ballot meta; ~410 active WGs).
// ---------------------------------------------------------------------------
__global__ __launch_bounds__(256, 2)
void convert_all_kernel(const float* __restrict__ x,
                        const float* __restrict__ w,
                        const float* __restrict__ mask,
                        unsigned short* __restrict__ xt,
                        unsigned short* __restrict__ wt) {
    const int b = blockIdx.x;
    if (b < 1024) {
        __shared__ unsigned short tlds[8][8][64];   // [kb_local][row][halves] 8KB
        const int mt = b >> 5;                       // 0..31
        const int rb = b & 31;                       // 8-row block 0..31
        const int t  = threadIdx.x;
        const size_t xrow0 = (size_t)(mt * TM + rb * 8) * IN_F;
        unsigned short* tb = xt + (size_t)(mt * 64) * 16384;   // this mt's tiles

        for (int j = 0; j < 8; ++j) {               // 8 col-chunks of 512 fp32
            // ---- phase 1: linear read + cvt + swizzled LDS store ----
#pragma unroll
            for (int l = 0; l < 4; ++l) {
                int id = l * 256 + t;               // 0..1023
                int r  = id >> 7, c4 = id & 127;    // row 0..7, f32x4 col
                f32x4 v = *(const f32x4*)(x + xrow0 + (size_t)r * IN_F
                                          + j * 512 + c4 * 4);
                u16x4 o;
#pragma unroll
                for (int k = 0; k < 4; ++k) o[k] = __half_as_ushort(__float2half_rn(v[k]));
                int kbl = c4 >> 4, c4k = c4 & 15;
                int slot = c4k >> 1, h0 = (c4k & 1) * 4;
                *(u16x4*)&tlds[kbl][r][((slot ^ r) << 3) + h0] = o;
            }
            __syncthreads();
            // ---- phase 2: contiguous 1KB/wave writes into 8 tiles ----
#pragma unroll
            for (int l = 0; l < 2; ++l) {
                int wid = l * 256 + t;              // 0..511
                int kk = wid >> 6, e = wid & 63;    // kb_local, element
                int row = e >> 3, s8 = e & 7;
                u16x8 v = *(const u16x8*)&tlds[kk][row][s8 * 8];
                unsigned short* tile = tb + (size_t)(j * 8 + kk) * 16384;
                *(u16x8*)&tile[(rb * 8 + row) * 64 + s8 * 8] = v;
            }
            __syncthreads();
        }
    } else {
        const int wb   = b - 1024;                  // 0..4095
        const int br   = wb >> 6, si = wb & 63;
        const int lane = threadIdx.x & 63;
        unsigned long long ball = mask_ballot(mask, br, lane);
        if (si >= __popcll(ball)) return;
        bool fl = ((ball >> lane) & 1ull) &&
                  (__popcll(ball & ((1ull << lane) - 1ull)) == si);
        unsigned long long m2 = __ballot(fl);
        const int kb = __ffsll(m2) - 1;
        unsigned short* tile = wt + (size_t)(br * NB + si) * 4096;

        f32x4 va[2], vb[2];
#pragma unroll
        for (int l = 0; l < 2; ++l) {
            int g   = threadIdx.x + l * 256;        // 0..511
            int row = g >> 3, slot = g & 7;
            const f32x4* src = (const f32x4*)(w + (size_t)(br * BS + row) * IN_F
                                              + kb * BS + slot * 8);
            va[l] = src[0];
            vb[l] = src[1];
        }
#pragma unroll
        for (int l = 0; l < 2; ++l) {
            int g   = threadIdx.x + l * 256;
            int row = g >> 3, slot = g & 7;
            *(u16x8*)&tile[row * 64 + ((slot ^ (row & 7)) << 3)] = pack8(va[l], vb[l]);
        }
    }
}

// async global->LDS, 16B per lane, contiguous 1KB per wave-instruction.
__device__ __forceinline__ void gll16(const void* g, void* l) {
    __builtin_amdgcn_global_load_lds(
        (const __attribute__((address_space(1))) unsigned int*)g,
        (__attribute__((address_space(3))) unsigned int*)l, 16, 0, 0);
}

// ---------------------------------------------------------------------------
// Kernel 2: block-sparse GEMM — byte-identical to r8's proven bsr_mfma5.
// fp16 MFMA, TM=256, wave tile 64x64 (4x4 rep), 2-phase LDS dbuf,
// inline ballot-meta, phase-chunked XCD swizzle (2-mt phases).
// ---------------------------------------------------------------------------
__global__ __launch_bounds__(256, 2)
void bsr_mfma5_kernel(const unsigned short* __restrict__ xt,
                      const unsigned short* __restrict__ wt,
                      const float* __restrict__ bias,
                      const float* __restrict__ mask,
                      float* __restrict__ out) {
    __shared__ unsigned short xs[2][TM * BS];   // 2 x 32 KB
    __shared__ unsigned short wsb[2][BS * BS];  // 2 x  8 KB

    const int b     = blockIdx.x;
    const int xcd   = b & 7;
    const int j     = b >> 3;           // 0..255
    const int phase = j >> 7;           // 0..1
    const int idx   = j & 127;          // br-fast within phase
    const int br    = idx >> 1;
    const int mt    = xcd * 4 + phase * 2 + (idx & 1);

    const int tid  = threadIdx.x;
    const int lane = tid & 63;
    const int wv   = tid >> 6;          // wave 0..3 -> rows [wv*64, wv*64+64)
    const int fr   = lane & 15;
    const int kg   = lane >> 4;

    unsigned long long ball = mask_ballot(mask, br, lane);
    const int cnt = __popcll(ball);

    f32x4 acc[4][4];
#pragma unroll
    for (int a = 0; a < 4; ++a)
#pragma unroll
        for (int c = 0; c < 4; ++c) acc[a][c] = (f32x4)0.0f;

    const char* xbase = (const char*)xt;
    const char* wbase = (const char*)wt;

    auto stage = [&](int kb, int si, int bb) {
        const char* xg = xbase + ((size_t)(mt * 64 + kb) << 15);   // 32 KB tiles
        const char* wg = wbase + ((size_t)(br * 64 + si) << 13);   //  8 KB tiles
        const int bx = wv * 8192;
#pragma unroll
        for (int q = 0; q < 8; ++q)
            gll16(xg + bx + q * 1024 + lane * 16, (char*)xs[bb] + bx + q * 1024);
        const int bw = wv * 2048;
#pragma unroll
        for (int q = 0; q < 2; ++q)
            gll16(wg + bw + q * 1024 + lane * 16, (char*)wsb[bb] + bw + q * 1024);
    };

    unsigned long long rem = ball;
    int cur = 0;
    if (cnt > 0) {
        int kb0 = __ffsll(rem) - 1;
        rem &= rem - 1;
        stage(kb0, 0, 0);
    }
    __syncthreads();

    for (int si = 0; si < cnt; ++si) {
        if (si + 1 < cnt) {
            int kbn = __ffsll(rem) - 1;
            rem &= rem - 1;
            stage(kbn, si + 1, cur ^ 1);
        }

#pragma unroll
        for (int ks = 0; ks < 2; ++ks) {
            f16x8 a[4], bfr[4];
#pragma unroll
            for (int mr = 0; mr < 4; ++mr) {
                int row = wv * 64 + mr * 16 + fr;
                a[mr] = *(const f16x8*)&xs[cur][row * 64 + (((ks * 4 + kg) ^ (row & 7)) << 3)];
            }
#pragma unroll
            for (int nr = 0; nr < 4; ++nr) {
                int row = nr * 16 + fr;
                bfr[nr] = *(const f16x8*)&wsb[cur][row * 64 + (((ks * 4 + kg) ^ (row & 7)) << 3)];
            }
#pragma unroll
            for (int mr = 0; mr < 4; ++mr)
#pragma unroll
                for (int nr = 0; nr < 4; ++nr)
                    acc[mr][nr] = __builtin_amdgcn_mfma_f32_16x16x32_f16(
                        a[mr], bfr[nr], acc[mr][nr], 0, 0, 0);
        }
        __syncthreads();
        cur ^= 1;
    }

    const int mbase = mt * TM;
    const int obase = br * BS;
#pragma unroll
    for (int nr = 0; nr < 4; ++nr) {
        float bv = bias[obase + nr * 16 + fr];
#pragma unroll
        for (int mr = 0; mr < 4; ++mr) {
#pragma unroll
            for (int r = 0; r < 4; ++r) {
                int m = mbase + wv * 64 + mr * 16 + kg * 4 + r;
                out[(size_t)m * OUT_F + obase + nr * 16 + fr] = acc[mr][nr][r] + bv;
            }
        }
    }
}

// ---------------------------------------------------------------------------
// Fallback (ws too small): fused in-loop conversion, single buffer.
// ---------------------------------------------------------------------------
__global__ __launch_bounds__(256, 3)
void bsr_fused_kernel(const float* __restrict__ x,
                      const float* __restrict__ w,
                      const float* __restrict__ bias,
                      const float* __restrict__ mask,
                      float* __restrict__ out) {
    __shared__ unsigned short xs[128 * BS];
    __shared__ unsigned short wsb[BS * BS];

    const int mt   = blockIdx.x;
    const int br   = blockIdx.y;
    const int tid  = threadIdx.x;
    const int lane = tid & 63;
    const int wv   = tid >> 6;
    const int fr   = lane & 15;
    const int kg   = lane >> 4;

    const int mbase = mt * 128;
    const int obase = br * BS;

    unsigned long long ball = mask_ballot(mask, br, lane);
    const int cnt = __popcll(ball);
    unsigned long long rem = ball;

    f32x4 acc[2][4];
#pragma unroll
    for (int a = 0; a < 2; ++a)
#pragma unroll
        for (int c = 0; c < 4; ++c) acc[a][c] = (f32x4)0.0f;

    for (int si = 0; si < cnt; ++si) {
        const int kb = __ffsll(rem) - 1;
        rem &= rem - 1;
        const int kbase = kb * BS;
#pragma unroll
        for (int l = 0; l < 4; ++l) {
            int g = tid + l * 256;
            int row = g >> 3, slot = g & 7;
            const f32x4* src = (const f32x4*)(x + (size_t)(mbase + row) * IN_F + kbase + slot * 8);
            *(u16x8*)&xs[row * BS + ((slot ^ (row & 7)) << 3)] = pack8(src[0], src[1]);
        }
#pragma unroll
        for (int l = 0; l < 2; ++l) {
            int g = tid + l * 256;
            int row = g >> 3, slot = g & 7;
            const f32x4* src = (const f32x4*)(w + (size_t)(obase + row) * IN_F + kbase + slot * 8);
            *(u16x8*)&wsb[row * BS + ((slot ^ (row & 7)) << 3)] = pack8(src[0], src[1]);
        }
        __syncthreads();
#pragma unroll
        for (int ks = 0; ks < 2; ++ks) {
            f16x8 a[2], bfr[4];
#pragma unroll
            for (int mr = 0; mr < 2; ++mr) {
                int row = wv * 32 + mr * 16 + fr;
                a[mr] = *(const f16x8*)&xs[row * BS + (((ks * 4 + kg) ^ (row & 7)) << 3)];
            }
#pragma unroll
            for (int nr = 0; nr < 4; ++nr) {
                int row = nr * 16 + fr;
                bfr[nr] = *(const f16x8*)&wsb[row * BS + (((ks * 4 + kg) ^ (row & 7)) << 3)];
            }
#pragma unroll
            for (int mr = 0; mr < 2; ++mr)
#pragma unroll
                for (int nr = 0; nr < 4; ++nr)
                    acc[mr][nr] = __builtin_amdgcn_mfma_f32_16x16x32_f16(
                        a[mr], bfr[nr], acc[mr][nr], 0, 0, 0);
        }
        __syncthreads();
    }

#pragma unroll
    for (int nr = 0; nr < 4; ++nr) {
        float bv = bias[obase + nr * 16 + fr];
#pragma unroll
        for (int mr = 0; mr < 2; ++mr) {
#pragma unroll
            for (int r = 0; r < 4; ++r) {
                int m = mbase + wv * 32 + mr * 16 + kg * 4 + r;
                out[(size_t)m * OUT_F + obase + nr * 16 + fr] = acc[mr][nr][r] + bv;
            }
        }
    }
}

extern "C" void kernel_launch(void* const* d_in, const int* in_sizes, int n_in,
                              void* d_out, int out_size, void* d_ws, size_t ws_size,
                              hipStream_t stream) {
    const float* x    = (const float*)d_in[0];
    const float* w    = (const float*)d_in[1];
    const float* bias = (const float*)d_in[2];
    const float* mask = (const float*)d_in[3];
    float* out = (float*)d_out;

    if (ws_size >= WS_NEEDED) {
        unsigned short* xt = (unsigned short*)((char*)d_ws + WS_XT_OFF);
        unsigned short* wt = (unsigned short*)((char*)d_ws + WS_WT_OFF);
        convert_all_kernel<<<1024 + NB * NB, 256, 0, stream>>>(x, w, mask, xt, wt);
        bsr_mfma5_kernel<<<NMT * NB, 256, 0, stream>>>(xt, wt, bias, mask, out);
    } else {
        dim3 grid(N_TOK / 128, NB);
        bsr_fused_kernel<<<grid, 256, 0, stream>>>(x, w, bias, mask, out);
    }
}